// Round 7
// baseline (422.271 us; speedup 1.0000x reference)
//
#include <hip/hip_runtime.h>
#include <stdint.h>

#define BLOCK 256
#define NPART 4            // clause-space partitions (2 XCDs per partition)
#define CHUNK 8192         // edges per work-steal grab (multiple of 4)

typedef int iv4 __attribute__((ext_vector_type(4)));

// ---------------------------------------------------------------------------
// ws layout:
//   [0]        nsat counter
//   [1]        done ticket
//   [2..5]     work-steal cursors[NPART]
//   [64 ..)    predbits : 1 bit per var, ((n_vars+63)/64)*8 bytes (~128 KB)
//   [satoff..) sat      : 1 BYTE per clause (~4 MB), plain stores
// All rebuilt every call (ws re-poisoned to 0xAA before every timed launch).
// ---------------------------------------------------------------------------

__global__ void prep(const float* __restrict__ preds,
                     unsigned long long* __restrict__ predbits,
                     uint4* __restrict__ satz,
                     unsigned* __restrict__ hdr,
                     int n_vars,
                     const int* __restrict__ nc_p) {
    const int gid = blockIdx.x * blockDim.x + threadIdx.x;
    const int stride = gridDim.x * blockDim.x;

    // pack preds -> 1 bit per var
    const int nv64 = (n_vars + 63) & ~63;
    for (int i = gid; i < nv64; i += stride) {
        bool b = false;
        if (i < n_vars) b = (__builtin_nontemporal_load(&preds[i]) >= 0.5f);
        const unsigned long long m = __ballot(b);
        if ((threadIdx.x & 63) == 0) predbits[i >> 6] = m;
    }

    // zero the clause-sat byte array
    const int nc = *nc_p;
    const int satw16 = (nc + 15) >> 4;
    const uint4 z = {0u, 0u, 0u, 0u};
    for (int i = gid; i < satw16; i += stride) satz[i] = z;

    if (gid < 8) hdr[gid] = 0u;   // nsat, done, cursors[4], pad
}

__global__ void scatter_sat(const int* __restrict__ lits,
                            const int* __restrict__ clauses,
                            const unsigned* __restrict__ predbits,
                            unsigned char* __restrict__ sat,
                            unsigned* __restrict__ cursors,
                            int n_edges, int n_vars,
                            const int* __restrict__ nc_p) {
    // physical XCD of this block -> clause partition (locality only; any
    // mapping is CORRECT, a wrong one just loses L2 residency).
    unsigned xcd;
    asm volatile("s_getreg_b32 %0, hwreg(HW_REG_XCC_ID)" : "=s"(xcd));
    const unsigned part = (xcd & 7u) >> 1;               // 8 XCDs -> 4 parts

    const int nc = *nc_p;
    const unsigned psize = (unsigned)((nc + NPART - 1) / NPART);
    const unsigned lo = part * psize;

    const iv4* __restrict__ l4 = reinterpret_cast<const iv4*>(lits);
    const iv4* __restrict__ c4 = reinterpret_cast<const iv4*>(clauses);

    __shared__ unsigned s_base;
    for (;;) {
        if (threadIdx.x == 0)
            s_base = atomicAdd(&cursors[part], (unsigned)CHUNK);
        __syncthreads();
        const unsigned base = s_base;
        __syncthreads();                  // s_base consumed before next grab
        if (base >= (unsigned)n_edges) break;
        const unsigned end = min(base + (unsigned)CHUNK, (unsigned)n_edges);

        // vectorized sweep (base is CHUNK-aligned -> multiple of 4)
        const int i4b = base >> 2;
        const int i4e = end >> 2;
        for (int i = i4b + (int)threadIdx.x; i < i4e; i += BLOCK) {
            const iv4 l = __builtin_nontemporal_load(&l4[i]);
            const iv4 c = __builtin_nontemporal_load(&c4[i]);
            #pragma unroll
            for (int k = 0; k < 4; ++k) {
                const int lit = l[k];
                const int cls = c[k];
                if ((unsigned)cls - lo < psize) {        // ours?
                    const bool pos = lit < n_vars;
                    const int v = pos ? lit : lit - n_vars;
                    const unsigned pb = predbits[v >> 5];
                    const bool pbit = ((pb >> (v & 31)) & 1u) != 0u;
                    if (pbit == pos) sat[cls] = (unsigned char)1;
                }
            }
        }
        // scalar tail within chunk (n_edges not multiple of 4)
        for (unsigned i = (unsigned)(i4e << 2) + threadIdx.x; i < end; i += BLOCK) {
            const int lit = lits[i];
            const int cls = clauses[i];
            if ((unsigned)cls - lo < psize) {
                const bool pos = lit < n_vars;
                const int v = pos ? lit : lit - n_vars;
                const unsigned pb = predbits[v >> 5];
                const bool pbit = ((pb >> (v & 31)) & 1u) != 0u;
                if (pbit == pos) sat[cls] = (unsigned char)1;
            }
        }
    }
}

__global__ void reduce_finalize(const uint4* __restrict__ sat16,
                                unsigned* __restrict__ nsat,
                                unsigned* __restrict__ done,
                                float* __restrict__ out,
                                const int* __restrict__ nc_p,
                                int n_vars) {
    const int nc = *nc_p;
    const int n16 = (nc + 15) >> 4;     // padded bytes are zeroed by prep
    const int tid = blockIdx.x * blockDim.x + threadIdx.x;
    const int stride = gridDim.x * blockDim.x;

    unsigned acc = 0;
    for (int i = tid; i < n16; i += stride) {
        const uint4 v = sat16[i];
        acc += __popc(v.x & 0x01010101u) + __popc(v.y & 0x01010101u) +
               __popc(v.z & 0x01010101u) + __popc(v.w & 0x01010101u);
    }

    #pragma unroll
    for (int off = 32; off > 0; off >>= 1) acc += __shfl_down(acc, off);

    __shared__ unsigned smem[BLOCK / 64];
    const int lane = threadIdx.x & 63;
    const int wid  = threadIdx.x >> 6;
    if (lane == 0) smem[wid] = acc;
    __syncthreads();

    if (threadIdx.x == 0) {
        unsigned bsum = 0;
        #pragma unroll
        for (int w = 0; w < BLOCK / 64; ++w) bsum += smem[w];
        atomicAdd(nsat, bsum);
        __threadfence();
        const unsigned ticket = atomicAdd(done, 1u);
        if (ticket == (unsigned)(gridDim.x - 1)) {
            const unsigned total = atomicAdd(nsat, 0u);
            *out = ((float)nc - (float)total) / (float)n_vars;
        }
    }
}

extern "C" void kernel_launch(void* const* d_in, const int* in_sizes, int n_in,
                              void* d_out, int out_size, void* d_ws, size_t ws_size,
                              hipStream_t stream) {
    const float* preds   = (const float*)d_in[0];
    const int*   lits    = (const int*)d_in[1];
    const int*   clauses = (const int*)d_in[2];
    const int*   nc_p    = (const int*)d_in[4];   // n_clauses (device scalar)
    const int    n_vars  = in_sizes[0];
    const int    n_edges = in_sizes[1];

    float* out = (float*)d_out;
    unsigned char* ws = (unsigned char*)d_ws;
    unsigned* hdr = (unsigned*)ws;                 // [0]=nsat [1]=done [2..5]=cursors
    unsigned long long* predbits = (unsigned long long*)(ws + 64);
    const size_t predbits_bytes = ((size_t)((n_vars + 63) / 64)) * 8;
    size_t satoff = 64 + predbits_bytes;
    satoff = (satoff + 63) & ~(size_t)63;          // 64B align sat array
    unsigned char* sat = ws + satoff;

    prep<<<2048, BLOCK, 0, stream>>>(preds, predbits, (uint4*)sat, hdr,
                                     n_vars, nc_p);
    scatter_sat<<<2048, BLOCK, 0, stream>>>(lits, clauses,
                                            (const unsigned*)predbits, sat,
                                            hdr + 2, n_edges, n_vars, nc_p);
    reduce_finalize<<<256, BLOCK, 0, stream>>>((const uint4*)sat,
                                               hdr, hdr + 1, out, nc_p, n_vars);
}